// Round 5
// baseline (4619.260 us; speedup 1.0000x reference)
//
#include <hip/hip_runtime.h>

// ---------------- problem constants ----------------
constexpr int kB = 2, kT = 1024, kD = 1024, kDI = 2048, kH = 16, kE = 8, kF = 2048;
constexpr int kBT = kB * kT;
constexpr float kEPS = 1.1920929e-07f;

typedef unsigned short u16;
typedef __bf16 bf16x8_t __attribute__((ext_vector_type(8)));
typedef float f32x4_t __attribute__((ext_vector_type(4)));

__device__ __forceinline__ u16 f2bf(float x) {
    unsigned int u = __builtin_bit_cast(unsigned int, x);
    return (u16)((u + 0x7FFFu + ((u >> 16) & 1u)) >> 16);
}
__device__ __forceinline__ float bf2f(u16 h) {
    return __builtin_bit_cast(float, (unsigned int)h << 16);
}
__device__ __forceinline__ float sigmoidf_(float v) { return 1.f / (1.f + expf(-v)); }

// split patterns (3 bits per segment): product pairing A-seg-i x B-seg-i
// A6 {0,1,0,1,2,0} x B6 {0,0,1,1,0,2} -> 00,10,01,11,20,02 (6-term, ~1e-7 residual)
// A3 {0,1,0}       x B3 {0,0,1}       -> 00,10,01          (3-term, ~2e-5 residual)
constexpr int PAT_A6 = (0) | (1 << 3) | (0 << 6) | (1 << 9) | (2 << 12) | (0 << 15);
constexpr int PAT_B6 = (0) | (0 << 3) | (1 << 6) | (1 << 9) | (0 << 12) | (2 << 15);
constexpr int PAT_A3 = (0) | (1 << 3) | (0 << 6);
constexpr int PAT_B3 = (0) | (0 << 3) | (1 << 6);

// ---------------- workspace layout (float units) ----------------
constexpr size_t MF = 1048576ull;
constexpr size_t O_HA6   = 0;                    // u16 2048x6144 = 6MF   (live -> fuse gemm)
constexpr size_t O_SSMO  = 6*MF;                 // f32 2MF (after WXZ dead)
constexpr size_t O_ATTNO = 8*MF;
constexpr size_t O_FUSEB = 10*MF;
constexpr size_t O_H2F   = 12*MF;
constexpr size_t O_H2B   = 14*MF;                // u16 1MF
constexpr size_t O_LAT   = 15*MF;                // f32 0.5MF
constexpr size_t O_LATA3 = 15*MF + 524288;       // u16 0.75MF
constexpr size_t O_LATB3 = 16*MF + 262144;       // u16 0.75MF
constexpr size_t O_QA3   = 17*MF;                // u16 3MF (grouped per-head)
constexpr size_t O_KB3   = 20*MF;                // u16 3MF
constexpr size_t O_VTB3  = 23*MF;                // u16 3MF
constexpr size_t O_CTX   = 26*MF;                // f32 2MF
// SSM-phase transients
constexpr size_t O_WXZ   = 6*MF;                 // u16 12MF [6,18)
constexpr size_t O_XZ    = 18*MF;                // f32 8MF [18,26)
constexpr size_t O_XIN   = 6*MF;                 // f32 4MF [6,10) (WXZ dead)
constexpr size_t O_EXPA  = 10*MF;
constexpr size_t O_CB    = 10*MF + 32768;
constexpr size_t O_CC    = 10*MF + 65536;
constexpr size_t O_PV1   = 10*MF + 131072;       // 1MF
constexpr size_t O_QV1   = 11*MF + 131072;
constexpr size_t O_S01   = 12*MF + 131072;
constexpr size_t O_YS    = 13*MF + 262144;       // 4MF [13.25,17.25)
constexpr size_t O_NORM6 = 28*MF;                // u16 12MF [28,40)
constexpr size_t O_WOUT  = 40*MF;                // u16 6MF [40,46)
// attention-phase transients
constexpr size_t O_WQ    = 28*MF;                // 1.5MF
constexpr size_t O_QF    = 29*MF + 524288;       // f32 2MF [29.5,31.5)
constexpr size_t O_WKVD  = 31*MF + 524288;       // 0.375MF
constexpr size_t O_WKUP  = 31*MF + 917504;       // 0.375MF
constexpr size_t O_KF    = 32*MF + 262144;       // f32 2MF
constexpr size_t O_WVUP  = 34*MF + 262144;       // 0.375MF
constexpr size_t O_VTF   = 34*MF + 655360;       // f32 2MF [34.625,36.625)
constexpr size_t O_SCORE = 28*MF;                // f32 8MF [28,36)
constexpr size_t O_P3    = 36*MF;                // u16 12MF [36,48)
constexpr size_t O_CTXA3 = 28*MF;                // u16 3MF
constexpr size_t O_WAO   = 31*MF;                // u16 1.5MF
constexpr size_t O_WFUSE = 28*MF;                // u16 3MF (after attno)
// MoE phase
constexpr size_t O_QG    = 17*MF;                // u16 8MF
constexpr size_t O_QU    = 25*MF;
constexpr size_t O_QD    = 33*MF;
constexpr size_t O_HH    = 41*MF;                // u16 5MF [41,46)
// misc
constexpr size_t O_MISC  = 48*MF + 262144;
constexpr size_t M_PROBS = O_MISC + 0;
constexpr size_t M_COUNT = O_MISC + 8;
constexpr size_t M_OFFS  = O_MISC + 16;
constexpr size_t M_CURS  = O_MISC + 25;
constexpr size_t M_NT    = O_MISC + 33;
constexpr size_t M_TILEE = O_MISC + 34;
constexpr size_t M_TILEB = O_MISC + 82;
constexpr size_t M_TOPI  = O_MISC + 130;
constexpr size_t M_TOPW  = O_MISC + 4226;
constexpr size_t M_PAIRT = O_MISC + 8322;
constexpr size_t M_PAIRW = O_MISC + 16514;
constexpr size_t M_PART  = O_MISC + 24706;
constexpr size_t M_THR   = O_MISC + 27778;
constexpr size_t WS_FLOATS = O_MISC + 32768;

// ---------------- misc small kernels ----------------
__global__ void zero_k(float* p, int n) {
    int i = blockIdx.x * blockDim.x + threadIdx.x;
    if (i < n) p[i] = 0.f;
}

__global__ __launch_bounds__(256) void rmsnorm_k(const float* __restrict__ x,
                                                 const float* __restrict__ w,
                                                 float* __restrict__ yf,
                                                 u16* __restrict__ yb, int C) {
    int row = blockIdx.x, tid = threadIdx.x;
    const float* xr = x + (size_t)row * C;
    float ss = 0.f;
    for (int c = tid * 4; c < C; c += 1024) {
        float4 v = *(const float4*)(xr + c);
        ss += v.x*v.x + v.y*v.y + v.z*v.z + v.w*v.w;
    }
    for (int off = 32; off; off >>= 1) ss += __shfl_xor(ss, off);
    __shared__ float red[4];
    if ((tid & 63) == 0) red[tid >> 6] = ss;
    __syncthreads();
    ss = red[0] + red[1] + red[2] + red[3];
    float r = rsqrtf(ss / C + kEPS);
    for (int c = tid * 4; c < C; c += 1024) {
        float4 v = *(const float4*)(xr + c);
        float4 g = *(const float4*)(w + c);
        v.x *= r * g.x; v.y *= r * g.y; v.z *= r * g.z; v.w *= r * g.w;
        if (yf) *(float4*)(yf + (size_t)row * C + c) = v;
        if (yb) {
            ushort4 o; o.x = f2bf(v.x); o.y = f2bf(v.y); o.z = f2bf(v.z); o.w = f2bf(v.w);
            *(ushort4*)(yb + (size_t)row * C + c) = o;
        }
    }
}

// rmsnorm + 6-term A-side split [a0|a1|a0|a1|a2|a0]
__global__ __launch_bounds__(256) void rmsnorm_splitA6_k(const float* __restrict__ x,
                                                         const float* __restrict__ w,
                                                         u16* __restrict__ dst, int C) {
    int row = blockIdx.x, tid = threadIdx.x;
    const float* xr = x + (size_t)row * C;
    float ss = 0.f;
    for (int c = tid * 4; c < C; c += 1024) {
        float4 v = *(const float4*)(xr + c);
        ss += v.x*v.x + v.y*v.y + v.z*v.z + v.w*v.w;
    }
    for (int off = 32; off; off >>= 1) ss += __shfl_xor(ss, off);
    __shared__ float red[4];
    if ((tid & 63) == 0) red[tid >> 6] = ss;
    __syncthreads();
    ss = red[0] + red[1] + red[2] + red[3];
    float r = rsqrtf(ss / C + kEPS);
    u16* drow = dst + (size_t)row * 6 * C;
    for (int c = tid * 4; c < C; c += 1024) {
        float4 v = *(const float4*)(xr + c);
        float4 g = *(const float4*)(w + c);
        float a[4] = {v.x*r*g.x, v.y*r*g.y, v.z*r*g.z, v.w*r*g.w};
        ushort4 c0, c1, c2;
        u16* p0 = (u16*)&c0; u16* p1 = (u16*)&c1; u16* p2 = (u16*)&c2;
#pragma unroll
        for (int j = 0; j < 4; j++) {
            float rr = a[j];
            p0[j] = f2bf(rr); rr -= bf2f(p0[j]);
            p1[j] = f2bf(rr); rr -= bf2f(p1[j]);
            p2[j] = f2bf(rr);
        }
        *(ushort4*)(drow + 0*C + c) = c0;
        *(ushort4*)(drow + 1*C + c) = c1;
        *(ushort4*)(drow + 2*C + c) = c0;
        *(ushort4*)(drow + 3*C + c) = c1;
        *(ushort4*)(drow + 4*C + c) = c2;
        *(ushort4*)(drow + 5*C + c) = c0;
    }
}

// generic splitter: src f32 [rows x C] -> dst u16 [rows x nseg*C], grouped by G columns
__global__ __launch_bounds__(256) void split_k(const float* __restrict__ src, u16* __restrict__ dst,
                                               int lgC, int lgG, int nseg, int pat, int total4) {
    int i = blockIdx.x * 256 + threadIdx.x;
    if (i >= total4) return;
    size_t e = (size_t)i * 4;
    int C = 1 << lgC;
    int row = (int)(e >> lgC), col = (int)(e & (C - 1));
    int g = col >> lgG, cg = col & ((1 << lgG) - 1);
    float4 v = *(const float4*)(src + e);
    float a[4] = {v.x, v.y, v.z, v.w};
    ushort4 comp[3];
#pragma unroll
    for (int j = 0; j < 4; j++) {
        float r = a[j];
#pragma unroll
        for (int c = 0; c < 3; c++) {
            u16 b = f2bf(r);
            ((u16*)&comp[c])[j] = b;
            r -= bf2f(b);
        }
    }
    u16* drow = dst + (size_t)row * ((size_t)nseg << lgC) + (((size_t)g * nseg) << lgG) + cg;
    for (int s = 0; s < nseg; s++) {
        int c = (pat >> (3 * s)) & 7;
        *(ushort4*)(drow + ((size_t)s << lgG)) = comp[c];
    }
}

// ---------------- MFMA bf16 NT GEMM: C[M,N] = A[M,K] * B[N,K]^T ----------------
template<int WC>
__global__ __launch_bounds__(256, 2) void mgemm(
    const u16* __restrict__ A, const u16* __restrict__ B, void* __restrict__ Cp,
    int K, int lda, int ldb, int ldc, int epi, int bh,
    long sAb, long sAh, long sBb, long sBh, long sCb, long sCh)
{
    constexpr int BM = 128, BN = WC * 64;
    constexpr int WM = BM / (4 / WC);
    constexpr int FM = WM / 16;
    constexpr int ASEG = (BM * 8) / 256;
    constexpr int BSEG = (BN * 8) / 256;
    int z = blockIdx.z, zb = z / bh, zh = z - zb * bh;
    const u16* Ab = A + (size_t)zb * sAb + (size_t)zh * sAh;
    const u16* Bb = B + (size_t)zb * sBb + (size_t)zh * sBh;
    int m0 = blockIdx.y * BM, n0 = blockIdx.x * BN;
    __shared__ __align__(16) u16 lsA[BM * 64];
    __shared__ __align__(16) u16 lsB[BN * 64];
    int tid = threadIdx.x;
    int w = tid >> 6, l = tid & 63;
    int wr = w / WC, wc = w % WC;
    int l15 = l & 15, kg = l >> 4;
    uint4 ra[ASEG], rb[BSEG];

    auto ld = [&](int kt) {
#pragma unroll
        for (int p = 0; p < ASEG; p++) {
            int s = tid + p * 256, row = s >> 3, kc = s & 7;
            ra[p] = *(const uint4*)(Ab + (size_t)(m0 + row) * lda + kt * 64 + kc * 8);
        }
#pragma unroll
        for (int p = 0; p < BSEG; p++) {
            int s = tid + p * 256, row = s >> 3, kc = s & 7;
            rb[p] = *(const uint4*)(Bb + (size_t)(n0 + row) * ldb + kt * 64 + kc * 8);
        }
    };
    auto st = [&]() {
#pragma unroll
        for (int p = 0; p < ASEG; p++) {
            int s = tid + p * 256, row = s >> 3, kc = s & 7;
            *(uint4*)(lsA + row * 64 + 8 * (kc ^ (row & 7))) = ra[p];
        }
#pragma unroll
        for (int p = 0; p < BSEG; p++) {
            int s = tid + p * 256, row = s >> 3, kc = s & 7;
            *(uint4*)(lsB + row * 64 + 8 * (kc ^ (row & 7))) = rb[p];
        }
    };

    f32x4_t acc[FM][4] = {};
    int nk = K >> 6;
    ld(0); st(); __syncthreads();
    for (int kt = 0; kt < nk; kt++) {
        if (kt + 1 < nk) ld(kt + 1);
#pragma unroll
        for (int ks = 0; ks < 2; ks++) {
            bf16x8_t af[FM], bfv[4];
            int ke = ks * 32 + kg * 8;
#pragma unroll
            for (int m = 0; m < FM; m++) {
                int r = wr * WM + m * 16 + l15;
                af[m] = *(const bf16x8_t*)(lsA + r * 64 + (ke ^ ((r & 7) << 3)));
            }
#pragma unroll
            for (int n = 0; n < 4; n++) {
                int c = wc * 64 + n * 16 + l15;
                bfv[n] = *(const bf16x8_t*)(lsB + c * 64 + (ke ^ ((c & 7) << 3)));
            }
#pragma unroll
            for (int m = 0; m < FM; m++)
#pragma unroll
                for (int n = 0; n < 4; n++)
                    acc[m][n] = __builtin_amdgcn_mfma_f32_16x16x32_bf16(af[m], bfv[n], acc[m][n], 0, 0, 0);
        }
        __syncthreads();
        if (kt + 1 < nk) st();
        __syncthreads();
    }
    if (epi == 0) {
        float* C = (float*)Cp + (size_t)zb * sCb + (size_t)zh * sCh;
#pragma unroll
        for (int m = 0; m < FM; m++) {
            int r0 = m0 + wr * WM + m * 16 + kg * 4;
#pragma unroll
            for (int n = 0; n < 4; n++) {
                int c = n0 + wc * 64 + n * 16 + l15;
#pragma unroll
                for (int j = 0; j < 4; j++)
                    C[(size_t)(r0 + j) * ldc + c] = acc[m][n][j];
            }
        }
    } else {
        u16* C = (u16*)Cp + (size_t)zb * sCb + (size_t)zh * sCh;
#pragma unroll
        for (int m = 0; m < FM; m++) {
            int r0 = m0 + wr * WM + m * 16 + kg * 4;
#pragma unroll
            for (int n = 0; n < 4; n++) {
                int c = n0 + wc * 64 + n * 16 + l15;
#pragma unroll
                for (int j = 0; j < 4; j++)
                    C[(size_t)(r0 + j) * ldc + c] = f2bf(acc[m][n][j]);
            }
        }
    }
}

// ---------------- SSM ----------------
__global__ void glu_k(const float* __restrict__ xz, float* __restrict__ xin) {
    int g = blockIdx.x * blockDim.x + threadIdx.x;
    if (g >= kBT * kDI / 4) return;
    int t = g >> 9, c4 = (g & 511) << 2;
    const float* row = xz + (size_t)t * 2 * kDI;
    float4 a = *(const float4*)(row + c4);
    float4 b = *(const float4*)(row + kDI + c4);
    float4 o;
    o.x = a.x * sigmoidf_(a.x) * sigmoidf_(b.x);
    o.y = a.y * sigmoidf_(a.y) * sigmoidf_(b.y);
    o.z = a.z * sigmoidf_(a.z) * sigmoidf_(b.z);
    o.w = a.w * sigmoidf_(a.w) * sigmoidf_(b.w);
    *(float4*)(xin + (size_t)t * kDI + c4) = o;
}

__global__ __launch_bounds__(256) void projabc_k(const float* __restrict__ xin,
                                                 const float* __restrict__ Aw,
                                                 const float* __restrict__ Bw,
                                                 const float* __restrict__ Cw,
                                                 float* __restrict__ expA,
                                                 float* __restrict__ Bc,
                                                 float* __restrict__ Cc) {
    int t = blockIdx.x;
    int wv = threadIdx.x >> 6, lane = threadIdx.x & 63;
    const float* Wp[12];
#pragma unroll
    for (int j = 0; j < 12; j++) {
        int o = wv * 12 + j;
        Wp[j] = (o < 16) ? (Aw + (size_t)o * kDI)
              : (o < 32) ? (Bw + (size_t)(o - 16) * kDI)
                         : (Cw + (size_t)(o - 32) * kDI);
    }
    float part[12] = {};
    const float* xr = xin + (size_t)t * kDI;
    for (int i = 0; i < kDI / 64; i++) {
        int d = lane + (i << 6);
        float xv = xr[d];
#pragma unroll
        for (int j = 0; j < 12; j++) part[j] = fmaf(xv, Wp[j][d], part[j]);
    }
#pragma unroll
    for (int j = 0; j < 12; j++)
        for (int off = 32; off; off >>= 1) part[j] += __shfl_xor(part[j], off);
    if (lane == 0) {
#pragma unroll
        for (int j = 0; j < 12; j++) {
            int o = wv * 12 + j;
            float v = part[j];
            if (o < 16) {
                float zc = fminf(fmaxf(v, -5.f), 0.f);
                expA[(size_t)t * 16 + o] = expf(-expf(zc));
            } else if (o < 32) Bc[(size_t)t * 16 + (o - 16)] = v;
            else Cc[(size_t)t * 16 + (o - 32)] = v;
        }
    }
}

__global__ __launch_bounds__(256) void scan_pass1(const float* __restrict__ xin,
                                                  const float* __restrict__ expA,
                                                  const float* __restrict__ Bc,
                                                  float* __restrict__ Pv, float* __restrict__ Qv) {
    int c = blockIdx.y;
    int ch = blockIdx.x * 256 + threadIdx.x;
    int b = ch >> 11, d = ch & (kDI - 1);
    __shared__ __align__(16) float sE[1024], sB[1024];
    size_t cbase = ((size_t)b * kT + c * 64) * 16;
    *(float4*)(sE + threadIdx.x * 4) = *(const float4*)(expA + cbase + threadIdx.x * 4);
    *(float4*)(sB + threadIdx.x * 4) = *(const float4*)(Bc + cbase + threadIdx.x * 4);
    __syncthreads();
    float s[16], p[16];
#pragma unroll
    for (int n = 0; n < 16; n++) { s[n] = 0.f; p[n] = 1.f; }
    const float* xp = xin + ((size_t)b * kT + c * 64) * kDI + d;
    for (int tl = 0; tl < 64; tl++) {
        float xv = xp[(size_t)tl * kDI];
        const float* e = sE + tl * 16;
        const float* bb = sB + tl * 16;
#pragma unroll
        for (int n = 0; n < 16; n++) {
            float ev = e[n];
            s[n] = s[n] * ev + xv * bb[n];
            p[n] *= ev;
        }
    }
    size_t ob = ((size_t)c * 4096 + ch) * 16;
#pragma unroll
    for (int q = 0; q < 16; q += 4) {
        *(float4*)(Pv + ob + q) = make_float4(p[q], p[q+1], p[q+2], p[q+3]);
        *(float4*)(Qv + ob + q) = make_float4(s[q], s[q+1], s[q+2], s[q+3]);
    }
}

__global__ __launch_bounds__(256) void scan_combine(const float* __restrict__ Pv,
                                                    const float* __restrict__ Qv,
                                                    float* __restrict__ S0) {
    int ch = blockIdx.x * 256 + threadIdx.x;
    float s[16] = {};
    for (int c = 0; c < 16; c++) {
        size_t base = ((size_t)c * 4096 + ch) * 16;
#pragma unroll
        for (int q = 0; q < 16; q += 4)
            *(float4*)(S0 + base + q) = make_float4(s[q], s[q+1], s[q+2], s[q+3]);
#pragma unroll
        for (int q = 0; q < 16; q += 4) {
            float4 pv = *(const float4*)(Pv + base + q);
            float4 qv = *(const float4*)(Qv + base + q);
            s[q+0] = s[q+0] * pv.x + qv.x;
            s[q+1] = s[q+1] * pv.y + qv.y;
            s[q+2] = s[q+2] * pv.z + qv.z;
            s[q+3] = s[q+3] * pv.w + qv.w;
        }
    }
}

__global__ __launch_bounds__(256) void scan_pass2(const float* __restrict__ xin,
                                                  const float* __restrict__ expA,
                                                  const float* __restrict__ Bc,
                                                  const float* __restrict__ Cc,
                                                  const float* __restrict__ S0,
                                                  float* __restrict__ ys) {
    int c = blockIdx.y;
    int ch = blockIdx.x * 256 + threadIdx.x;
    int b = ch >> 11, d = ch & (kDI - 1);
    __shared__ __align__(16) float sE[1024], sB[1024], sC[1024];
    size_t cbase = ((size_t)b * kT + c * 64) * 16;
    *(float4*)(sE + threadIdx.x * 4) = *(const float4*)(expA + cbase + threadIdx.x * 4);
    *(float4*)(sB + threadIdx.x * 4) = *(const float4*)(Bc + cbase + threadIdx.x * 4);
    *(float4*)(sC + threadIdx.x * 4) = *(const float4*)(Cc + cbase + threadIdx.x * 4);
    __syncthreads();
    float s[16];
    size_t sb = ((size_t)c * 4096 + ch) * 16;
#pragma unroll
    for (int q = 0; q < 16; q += 4) {
        float4 v = *(const float4*)(S0 + sb + q);
        s[q] = v.x; s[q+1] = v.y; s[q+2] = v.z; s[q+3] = v.w;
    }
    const float* xp = xin + ((size_t)b * kT + c * 64) * kDI + d;
    float* yp = ys + ((size_t)b * kT + c * 64) * kDI + d;
    for (int tl = 0; tl < 64; tl++) {
        float xv = xp[(size_t)tl * kDI];
        const float* e = sE + tl * 16;
        const float* bb = sB + tl * 16;
        const float* cc = sC + tl * 16;
        float y = 0.f;
#pragma unroll
        for (int n = 0; n < 16; n++) {
            float ev = e[n];
            s[n] = s[n] * ev + xv * bb[n];
            y = fmaf(s[n], cc[n], y);
        }
        yp[(size_t)tl * kDI] = y;
    }
}

// ---------------- attention softmax: f32 scores -> 2-comp split probs [p0|p1|p0] ----------------
__global__ __launch_bounds__(256) void softmax_p3(const float* __restrict__ S, u16* __restrict__ P3) {
    size_t row = blockIdx.x;
    const float* r = S + row * 1024;
    u16* pr = P3 + row * 3072;
    int tid = threadIdx.x;
    float4 v = *(const float4*)(r + tid * 4);
    v.x *= 0.125f; v.y *= 0.125f; v.z *= 0.125f; v.w *= 0.125f;
    float mx = fmaxf(fmaxf(v.x, v.y), fmaxf(v.z, v.w));
    for (int off = 32; off; off >>= 1) mx = fmaxf(mx, __shfl_xor(mx, off));
    __shared__ float red[4];
    if ((tid & 63) == 0) red[tid >> 6] = mx;
    __syncthreads();
    mx = fmaxf(fmaxf(red[0], red[1]), fmaxf(red[2], red[3]));
    v.x = expf(v.x - mx); v.y = expf(v.y - mx); v.z = expf(v.z - mx); v.w = expf(v.w - mx);
    float sm = v.x + v.y + v.z + v.w;
    for (int off = 32; off; off >>= 1) sm += __shfl_xor(sm, off);
    __syncthreads();
    if ((tid & 63) == 0) red[tid >> 6] = sm;
    __syncthreads();
    sm = red[0] + red[1] + red[2] + red[3];
    float inv = 1.f / sm;
    float p[4] = {v.x * inv, v.y * inv, v.z * inv, v.w * inv};
    ushort4 c0, c1;
    u16* p0 = (u16*)&c0; u16* p1 = (u16*)&c1;
#pragma unroll
    for (int j = 0; j < 4; j++) {
        p0[j] = f2bf(p[j]);
        p1[j] = f2bf(p[j] - bf2f(p0[j]));
    }
    *(ushort4*)(pr + tid * 4) = c0;
    *(ushort4*)(pr + 1024 + tid * 4) = c1;
    *(ushort4*)(pr + 2048 + tid * 4) = c0;
}

// ---------------- gated fuse ----------------
__global__ void fuse_k(const float* __restrict__ x, const float* __restrict__ fl,
                       const float* __restrict__ ssm, const float* __restrict__ attn,
                       float* __restrict__ out) {
    int g = blockIdx.x * blockDim.x + threadIdx.x;
    if (g >= kBT * kD / 4) return;
    float4 xv = ((const float4*)x)[g];
    float4 fv = ((const float4*)fl)[g];
    float4 sv = ((const float4*)ssm)[g];
    float4 av = ((const float4*)attn)[g];
    float4 o;
    float gt;
    gt = sigmoidf_(fv.x); o.x = xv.x + gt * sv.x + (1.f - gt) * av.x;
    gt = sigmoidf_(fv.y); o.y = xv.y + gt * sv.y + (1.f - gt) * av.y;
    gt = sigmoidf_(fv.z); o.z = xv.z + gt * sv.z + (1.f - gt) * av.z;
    gt = sigmoidf_(fv.w); o.w = xv.w + gt * sv.w + (1.f - gt) * av.w;
    ((float4*)out)[g] = o;
}

// ---------------- ternary quantization ----------------
__global__ __launch_bounds__(256) void absmean_partial(const float* __restrict__ w,
                                                       float* __restrict__ part) {
    size_t i0 = ((size_t)blockIdx.x * 256 + threadIdx.x) * 4;
    float s = 0.f;
    for (int it = 0; it < 16; it++) {
        float4 v = *(const float4*)(w + i0 + (size_t)it * 1048576);
        s += fabsf(v.x) + fabsf(v.y) + fabsf(v.z) + fabsf(v.w);
    }
    for (int off = 32; off; off >>= 1) s += __shfl_xor(s, off);
    __shared__ float red[4];
    if ((threadIdx.x & 63) == 0) red[threadIdx.x >> 6] = s;
    __syncthreads();
    if (threadIdx.x == 0) part[blockIdx.x] = red[0] + red[1] + red[2] + red[3];
}

__global__ __launch_bounds__(256) void thresh_k(const float* __restrict__ part,
                                                float* __restrict__ thresh) {
    double s = 0.0;
    for (int i = threadIdx.x; i < 1024; i += 256) s += (double)part[i];
    for (int off = 32; off; off >>= 1) s += __shfl_xor(s, off);
    __shared__ double red[4];
    if ((threadIdx.x & 63) == 0) red[threadIdx.x >> 6] = s;
    __syncthreads();
    if (threadIdx.x == 0) {
        double tot = red[0] + red[1] + red[2] + red[3];
        *thresh = (float)(0.5 * tot / 16777216.0);
    }
}

__global__ void quantb_k(const float* __restrict__ w, const float* __restrict__ thresh,
                         u16* __restrict__ q) {
    float t = *thresh;
    size_t i = ((size_t)blockIdx.x * 256 + threadIdx.x) * 4;
    if (i >= 16777216ull) return;
    float4 v = *(const float4*)(w + i);
    ushort4 o;
    o.x = (v.x > t) ? 0x3F80 : (v.x < -t) ? 0xBF80 : 0;
    o.y = (v.y > t) ? 0x3F80 : (v.y < -t) ? 0xBF80 : 0;
    o.z = (v.z > t) ? 0x3F80 : (v.z < -t) ? 0xBF80 : 0;
    o.w = (v.w > t) ? 0x3F80 : (v.w < -t) ? 0xBF80 : 0;
    *(ushort4*)(q + i) = o;
}

// ---------------- router + routing bookkeeping ----------------
__global__ __launch_bounds__(256) void router_k(const float* __restrict__ h2,
                                                const float* __restrict__ rw,
                                                int* __restrict__ topi, float* __restrict__ topw,
                                                int* __restrict__ counts, float* __restrict__ probsSum) {
    int wv = threadIdx.x >> 6, lane = threadIdx.x & 63;
    int t = blockIdx.x * 4 + wv;
    const float* hr = h2 + (size_t)t * kD;
    float part[8] = {};
    for (int i = 0; i < 16; i++) {
        int d = lane + (i << 6);
        float hv = hr[d];
#pragma unroll
        for (int e = 0; e < 8; e++) part[e] = fmaf(hv, rw[e * kD + d], part[e]);
    }
#pragma unroll
    for (int e = 0; e < 8; e++)
        for (int off = 32; off; off >>= 1) part[e] += __shfl_xor(part[e], off);
    float mx = part[0];
#pragma unroll
    for (int e = 1; e < 8; e++) mx = fmaxf(mx, part[e]);
    float p[8], sum = 0.f;
#pragma unroll
    for (int e = 0; e < 8; e++) { p[e] = expf(part[e] - mx); sum += p[e]; }
    float inv = 1.f / sum;
#pragma unroll
    for (int e = 0; e < 8; e++) p[e] *= inv;
    int i1 = 0; float p1 = p[0];
#pragma unroll
    for (int e = 1; e < 8; e++) if (p[e] > p1) { p1 = p[e]; i1 = e; }
    int i2 = -1; float p2 = -1.f;
#pragma unroll
    for (int e = 0; e < 8; e++) if (e != i1 && p[e] > p2) { p2 = p[e]; i2 = e; }
    if (lane == 0) {
        float wsum = p1 + p2 + 1e-9f;
        topi[2 * t] = i1; topi[2 * t + 1] = i2;
        topw[2 * t] = p1 / wsum; topw[2 * t + 1] = p2 / wsum;
        atomicAdd(&counts[i1], 1); atomicAdd(&counts[i2], 1);
#pragma unroll
        for (int e = 0; e < 8; e++) atomicAdd(&probsSum[e], p[e]);
    }
}

__global__ void route_offsets_k(const int* __restrict__ counts, int* offs, int* cursor,
                                int* pairTok, float* pairW, int* tileE, int* tileB, int* nTiles) {
    if (threadIdx.x != 0 || blockIdx.x != 0) return;
    int off = 0, tc = 0;
    for (int e = 0; e < 8; e++) {
        offs[e] = off; cursor[e] = off;
        int c = counts[e];
        int padded = (c + 127) & ~127;
        for (int p = c; p < padded; p++) { pairTok[off + p] = -1; pairW[off + p] = 0.f; }
        for (int j = 0; j < (padded >> 7); j++) { tileE[tc] = e; tileB[tc] = off + (j << 7); tc++; }
        off += padded;
    }
    offs[8] = off;
    *nTiles = tc;
    for (int j = tc; j < 48; j++) { tileE[j] = 0; tileB[j] = 0; }
}

__global__ void scatter_k(const int* __restrict__ topi, const float* __restrict__ topw,
                          int* cursor, int* pairTok, float* pairW) {
    int t = blockIdx.x * 256 + threadIdx.x;
    if (t >= kBT) return;
    for (int j = 0; j < 2; j++) {
        int e = topi[2 * t + j];
        int pos = atomicAdd(&cursor[e], 1);
        pairTok[pos] = t;
        pairW[pos] = topw[2 * t + j];
    }
}

// ---------------- MoE expert GEMMs (bf16 ternary weights, MFMA) ----------------
__global__ __launch_bounds__(256, 2) void moe_gu_m(const u16* __restrict__ h2b,
    const u16* __restrict__ qg, const u16* __restrict__ qu,
    const float* __restrict__ gate_g, const float* __restrict__ up_g,
    const int* __restrict__ tileE, const int* __restrict__ tileB, const int* __restrict__ nTiles,
    const int* __restrict__ pairTok, u16* __restrict__ hh)
{
    if ((int)blockIdx.y >= *nTiles) return;
    int te = tileE[blockIdx.y], base = tileB[blockIdx.y];
    __shared__ __align__(16) u16 lsA[128 * 64], lsG[64 * 64], lsU[64 * 64];
    __shared__ int sTok[128];
    int tid = threadIdx.x;
    if (tid < 128) { int tk = pairTok[base + tid]; sTok[tid] = tk < 0 ? 0 : tk; }
    __syncthreads();
    int w = tid >> 6, l = tid & 63, l15 = l & 15, kg = l >> 4;
    int n0 = blockIdx.x << 6;
    const u16* Gb = qg + ((size_t)te * kF + n0) * kD;
    const u16* Ub = qu + ((size_t)te * kF + n0) * kD;
    uint4 ra[4], rg[2], ru[2];
    auto ld = [&](int kt) {
#pragma unroll
        for (int p = 0; p < 4; p++) {
            int s = tid + p * 256, row = s >> 3, kc = s & 7;
            ra[p] = *(const uint4*)(h2b + (size_t)sTok[row] * kD + kt * 64 + kc * 8);
        }
#pragma unroll
        for (int p = 0; p < 2; p++) {
            int s = tid + p * 256, row = s >> 3, kc = s & 7;
            rg[p] = *(const uint4*)(Gb + (size_t)row * kD + kt * 64 + kc * 8);
            ru[p] = *(const uint4*)(Ub + (size_t)row * kD + kt * 64 + kc * 8);
        }
    };
    auto st = [&]() {
#pragma unroll
        for (int p = 0; p < 4; p++) {
            int s = tid + p * 256, row = s >> 3, kc = s & 7;
            *(uint4*)(lsA + row * 64 + 8 * (kc ^ (row & 7))) = ra[p];
        }
#pragma unroll
        for (int p = 0; p < 2; p++) {
            int s = tid + p * 256, row = s >> 3, kc = s & 7;
            *(uint4*)(lsG + row * 64 + 8 * (kc ^ (row & 7))) = rg[p];
            *(uint4*)(lsU + row * 64 + 8 * (kc ^ (row & 7))) = ru[p];
        }
    };
    f32x4_t ag[2][4] = {}, au[2][4] = {};
    ld(0); st(); __syncthreads();
    for (int kt = 0; kt < 16; kt++) {
        if (kt + 1 < 16) ld(kt + 1);
#pragma unroll
        for (int ks = 0; ks < 2; ks++) {
            bf16x8_t af[2], gf[4], uf[4];
            int ke = ks * 32 + kg * 8;
#pragma unroll
            for (int m = 0; m < 2; m++) {
                int r = w * 32 + m * 16 + l15;
                af[m] = *(const bf16x8_t*)(lsA + r * 64 + (ke ^ ((r & 7) << 3)));
            }
#pragma unroll
            for (int n = 0; n < 4; n++) {
                int c = n * 16 + l15;
                gf[n] = *(const bf16x8_t*)(lsG + c * 64 + (ke ^ ((c & 7) << 3)));
                uf[n] = *(const bf16x8_t*)(lsU + c * 64 + (ke ^ ((c & 7) << 3)));
            }
#pragma unroll
            for (int m = 0; m < 2; m++)
#pragma unroll
                for (int n = 0; n < 4; n++) {
                    ag[m][n] = __builtin_amdgcn_mfma_f32_16x16x32_bf16(af[m], gf[n], ag[m][n], 0, 0, 0);
                    au[m][n] = __builtin_amdgcn_mfma_f32_16x16x32_bf16(af[m], uf[n], au[m][n], 0, 0, 0);
                }
        }
        __syncthreads();
        if (kt + 1 < 16) st();
        __syncthreads();
    }
    float gs = gate_g[te], us = up_g[te];
#pragma unroll
    for (int m = 0; m < 2; m++) {
        int r0 = w * 32 + m * 16 + kg * 4;
#pragma unroll
        for (int n = 0; n < 4; n++) {
            int c = n0 + n * 16 + l15;
#pragma unroll
            for (int j = 0; j < 4; j++) {
                float g = ag[m][n][j] * gs, u = au[m][n][j] * us;
                float hv = g * sigmoidf_(g) * u;
                hh[(size_t)(base + r0 + j) * kF + c] = f2bf(hv);
            }
        }
    }
}

__global__ __launch_bounds__(256, 2) void moe_down_m(const u16* __restrict__ hh,
    const u16* __restrict__ qd, const float* __restrict__ down_g,
    const int* __restrict__ tileE, const int* __restrict__ tileB, const int* __restrict__ nTiles,
    const int* __restrict__ pairTok, const float* __restrict__ pairW,
    float* __restrict__ out)
{
    if ((int)blockIdx.y >= *nTiles) return;
    int te = tileE[blockIdx.y], base = tileB[blockIdx.y];
    __shared__ __align__(16) u16 lsA[128 * 64], lsB[128 * 64];
    __shared__ int sTok[128];
    __shared__ float sW[128];
    int tid = threadIdx.x;
    if (tid < 128) { sTok[tid] = pairTok[base + tid]; sW[tid] = pairW[base + tid]; }
    __syncthreads();
    int w = tid >> 6, l = tid & 63, l15 = l & 15, kg = l >> 4;
    int wr = w >> 1, wc = w & 1;
    int n0 = blockIdx.x << 7;
    const u16* Ab = hh + (size_t)base * kF;
    const u16* Bb = qd + ((size_t)te * kD + n0) * kF;
    uint4 ra[4], rb[4];
    auto ld = [&](int kt) {
#pragma unroll
        for (int p = 0; p < 4; p++) {
            int s = tid + p * 256, row = s >> 3, kc = s & 7;
            ra[p] = *(const uint4*)(Ab + (size_t)row * kF + kt * 64 + kc * 8);
            rb[p] = *(const uint4*)(Bb + (size_t)row * kF + kt * 64 + kc * 8);
        }
    };
    auto st = [&]() {
#pragma unroll
        for (int p = 0; p < 4; p++) {
            int s = tid + p * 256, row = s >> 3, kc = s & 7;
            *(uint4*)(lsA + row * 64 + 8 * (kc ^ (row & 7))) = ra[p];
            *(uint4*)(lsB + row * 64 + 8 * (kc ^ (row & 7))) = rb[p];
        }
    };
    f32x4_t acc[4][4] = {};
    ld(0); st(); __syncthreads();
    for (int kt = 0; kt < 32; kt++) {
        if (kt + 1 < 32) ld(kt + 1);
#pragma unroll
        for (int ks = 0; ks < 2; ks++) {
            bf16x8_t af[4], bfv[4];
            int ke = ks * 32 + kg * 8;
#pragma unroll
            for (int m = 0; m < 4; m++) {
                int r = wr * 64 + m * 16 + l15;
                af[m] = *(const bf16x8_t*)(lsA + r * 64 + (ke ^ ((r & 7) << 3)));
            }
#pragma unroll
            for (int n = 0; n < 4; n++) {
                int c = wc * 64 + n * 16 + l15;
                bfv[n] = *(const bf16x8_t*)(lsB + c * 64 + (ke ^ ((c & 7) << 3)));
            }
#pragma unroll
            for (int m = 0; m < 4; m++)
#pragma unroll
                for (int n = 0; n < 4; n++)
                    acc[m][n] = __builtin_amdgcn_mfma_f32_16x16x32_bf16(af[m], bfv[n], acc[m][n], 0, 0, 0);
        }
        __syncthreads();
        if (kt + 1 < 32) st();
        __syncthreads();
    }
    float ds = down_g[te];
#pragma unroll
    for (int m = 0; m < 4; m++) {
        int r0 = wr * 64 + m * 16 + kg * 4;
#pragma unroll
        for (int n = 0; n < 4; n++) {
            int c = n0 + wc * 64 + n * 16 + l15;
#pragma unroll
            for (int j = 0; j < 4; j++) {
                int rr = r0 + j;
                int tok = sTok[rr];
                if (tok >= 0)
                    atomicAdd(&out[(size_t)tok * kD + c], acc[m][n][j] * sW[rr] * ds);
            }
        }
    }
}

__global__ void aux_k(const float* __restrict__ probsSum, float* __restrict__ out) {
    if (threadIdx.x != 0 || blockIdx.x != 0) return;
    float ent = 0.f;
    for (int e = 0; e < 8; e++) {
        float p = probsSum[e] * (1.f / (float)kBT);
        ent -= p * logf(p + 1e-9f);
    }
    out[0] = -ent * 0.01f;
}

// ---------------- launch ----------------
extern "C" void kernel_launch(void* const* d_in, const int* in_sizes, int n_in,
                              void* d_out, int out_size, void* d_ws, size_t ws_size,
                              hipStream_t stream) {
    const float* x       = (const float*)d_in[0];
    const float* n1w     = (const float*)d_in[1];
    const float* n2w     = (const float*)d_in[2];
    const float* ssm_in_w= (const float*)d_in[3];
    const float* ssm_A_w = (const float*)d_in[4];
    const float* ssm_B_w = (const float*)d_in[5];
    const float* ssm_C_w = (const float*)d_in[6];
    const float* ssm_nw  = (const float*)d_in[7];
    const float* ssm_ow  = (const float*)d_in[8];
    const float* q_w     = (const float*)d_in[9];
    const float* kvd_w   = (const float*)d_in[10];
    const float* kup_w   = (const float*)d_in[11];
    const float* vup_w   = (const float*)d_in[12];
    const float* ao_w    = (const float*)d_in[13];
    const float* fuse_w  = (const float*)d_in[14];
    const float* rtr_w   = (const float*)d_in[15];
    const float* eg_w    = (const float*)d_in[16];
    const float* eu_w    = (const float*)d_in[17];
    const float* ed_w    = (const float*)d_in[18];
    const float* eg_g    = (const float*)d_in[19];
    const float* eu_g    = (const float*)d_in[20];
    const float* ed_g    = (const float*)d_in[21];
    float* out = (float*)d_out;
    float* wsf = (float*)d_ws;
    if (ws_size < WS_FLOATS * sizeof(float)) return;

    u16* hA6   = (u16*)(wsf + O_HA6);
    float* ssmo  = wsf + O_SSMO;
    float* attno = wsf + O_ATTNO;
    float* fuseb = wsf + O_FUSEB;
    float* h2f   = wsf + O_H2F;
    u16* h2b   = (u16*)(wsf + O_H2B);
    float* latf  = wsf + O_LAT;
    u16* latA3 = (u16*)(wsf + O_LATA3);
    u16* latB3 = (u16*)(wsf + O_LATB3);
    u16* qA3   = (u16*)(wsf + O_QA3);
    u16* kB3   = (u16*)(wsf + O_KB3);
    u16* vtB3  = (u16*)(wsf + O_VTB3);
    float* ctx   = wsf + O_CTX;
    u16* wxz   = (u16*)(wsf + O_WXZ);
    float* xz    = wsf + O_XZ;
    float* xin   = wsf + O_XIN;
    float* expA  = wsf + O_EXPA;
    float* cB    = wsf + O_CB;
    float* cC    = wsf + O_CC;
    float* Pv    = wsf + O_PV1;
    float* Qv    = wsf + O_QV1;
    float* S0    = wsf + O_S01;
    float* ys    = wsf + O_YS;
    u16* norm6 = (u16*)(wsf + O_NORM6);
    u16* wout  = (u16*)(wsf + O_WOUT);
    u16* wq    = (u16*)(wsf + O_WQ);
    float* qf    = wsf + O_QF;
    u16* wkvd  = (u16*)(wsf + O_WKVD);
    u16* wkup  = (u16*)(wsf + O_WKUP);
    float* kf    = wsf + O_KF;
    u16* wvup  = (u16*)(wsf + O_WVUP);
    float* vtf   = wsf + O_VTF;
    float* score = wsf + O_SCORE;
    u16* P3    = (u16*)(wsf + O_P3);
    u16* ctxA3 = (u16*)(wsf + O_CTXA3);
    u16* wao   = (u16*)(wsf + O_WAO);
    u16* wfuse = (u16*)(wsf + O_WFUSE);
    u16* qg    = (u16*)(wsf + O_QG);
    u16* qu    = (u16*)(wsf + O_QU);
    u16* qd    = (u16*)(wsf + O_QD);
    u16* hh    = (u16*)(wsf + O_HH);
    float* probs  = wsf + M_PROBS;
    int* counts   = (int*)(wsf + M_COUNT);
    int* offs     = (int*)(wsf + M_OFFS);
    int* cursor   = (int*)(wsf + M_CURS);
    int* nTiles   = (int*)(wsf + M_NT);
    int* tileE    = (int*)(wsf + M_TILEE);
    int* tileB    = (int*)(wsf + M_TILEB);
    int* topi     = (int*)(wsf + M_TOPI);
    float* topw   = wsf + M_TOPW;
    int* pairT    = (int*)(wsf + M_PAIRT);
    float* pairW  = wsf + M_PAIRW;
    float* part   = wsf + M_PART;
    float* thr    = wsf + M_THR;

    zero_k<<<1, 64, 0, stream>>>(probs, 16);
    // h = rmsnorm(x) -> 6-term A-split (prefix K=3072 serves as 3-term)
    rmsnorm_splitA6_k<<<kBT, 256, 0, stream>>>(x, n1w, hA6, 1024);
    // xz = h @ ssm_in_w^T, 6-term (f32-grade)
    split_k<<<4096, 256, 0, stream>>>(ssm_in_w, wxz, 10, 10, 6, PAT_B6, 1048576);
    mgemm<2><<<dim3(32, 16, 1), 256, 0, stream>>>(hA6, wxz, xz, 6144, 6144, 6144, 4096, 0, 1, 0, 0, 0, 0, 0, 0);
    glu_k<<<(kBT * kDI / 4) / 256, 256, 0, stream>>>(xz, xin);
    projabc_k<<<kBT, 256, 0, stream>>>(xin, ssm_A_w, ssm_B_w, ssm_C_w, expA, cB, cC);
    scan_pass1<<<dim3(16, 16, 1), 256, 0, stream>>>(xin, expA, cB, Pv, Qv);
    scan_combine<<<16, 256, 0, stream>>>(Pv, Qv, S0);
    scan_pass2<<<dim3(16, 16, 1), 256, 0, stream>>>(xin, expA, cB, cC, S0, ys);
    // ssmo = rmsnorm(ys) @ ssm_ow^T, 6-term
    rmsnorm_splitA6_k<<<kBT, 256, 0, stream>>>(ys, ssm_nw, norm6, 2048);
    split_k<<<2048, 256, 0, stream>>>(ssm_ow, wout, 11, 11, 6, PAT_B6, 524288);
    mgemm<2><<<dim3(8, 16, 1), 256, 0, stream>>>(norm6, wout, ssmo, 12288, 12288, 12288, 1024, 0, 1, 0, 0, 0, 0, 0, 0);
    // MLA attention (3-term splits)
    split_k<<<1024, 256, 0, stream>>>(q_w, wq, 10, 10, 3, PAT_B3, 262144);
    mgemm<2><<<dim3(8, 16, 1), 256, 0, stream>>>(hA6, wq, qf, 3072, 6144, 3072, 1024, 0, 1, 0, 0, 0, 0, 0, 0);
    split_k<<<256, 256, 0, stream>>>(kvd_w, wkvd, 10, 10, 3, PAT_B3, 65536);
    mgemm<2><<<dim3(2, 16, 1), 256, 0, stream>>>(hA6, wkvd, latf, 3072, 6144, 3072, 256, 0, 1, 0, 0, 0, 0, 0, 0);
    split_k<<<512, 256, 0, stream>>>(latf, latA3, 8, 8, 3, PAT_A3, 131072);
    split_k<<<512, 256, 0, stream>>>(latf, latB3, 8, 8, 3, PAT_B3, 131072);
    split_k<<<256, 256, 0, stream>>>(kup_w, wkup, 8, 8, 3, PAT_B3, 65536);
    mgemm<2><<<dim3(8, 16, 1), 256, 0, stream>>>(latA3, wkup, kf, 768, 768, 768, 1024, 0, 1, 0, 0, 0, 0, 0, 0);
    split_k<<<256, 256, 0, stream>>>(vup_w, wvup, 8, 8, 3, PAT_A3, 65536);
    // vt[b][d][t] = vup[d,:] . lat[b][t,:]
    mgemm<2><<<dim3(8, 8, 2), 256, 0, stream>>>(wvup, latB3, vtf, 768, 768, 768, 1024, 0, 1,
                                                0, 0, 786432, 0, 1048576, 0);
    // splits for attention core: q A3 grouped per head (G=64), k B3 grouped, vt B3 plain
    split_k<<<2048, 256, 0, stream>>>(qf, qA3, 10, 6, 3, PAT_A3, 524288);
    split_k<<<2048, 256, 0, stream>>>(kf, kB3, 10, 6, 3, PAT_B3, 524288);
    split_k<<<2048, 256, 0, stream>>>(vtf, vtB3, 10, 10, 3, PAT_B3, 524288);
    // attention loop over 4 head-groups (both b per launch; z = b*4 + head-in-group)
    for (int hg = 0; hg < 4; hg++) {
        mgemm<2><<<dim3(8, 8, 8), 256, 0, stream>>>(qA3 + hg * 768, kB3 + hg * 768, score,
                                                    192, 3072, 3072, 1024, 0, 4,
                                                    3145728, 192, 3145728, 192, 4194304, 1048576);
        softmax_p3<<<8192, 256, 0, stream>>>(score, P3);
        mgemm<1><<<dim3(1, 8, 8), 256, 0, stream>>>(P3, vtB3 + (size_t)hg * 786432, ctx + hg * 256,
                                                    3072, 3072, 3072, 1024, 0, 4,
                                                    12582912, 3145728, 3145728, 196608, 1048576, 64);
    }
    split_k<<<2048, 256, 0, stream>>>(ctx, ctxA3, 10, 10, 3, PAT_A3, 524288);
    split_k<<<1024, 256, 0, stream>>>(ao_w, wao, 10, 10, 3, PAT_B3, 262144);
    mgemm<2><<<dim3(8, 16, 1), 256, 0, stream>>>(ctxA3, wao, attno, 3072, 3072, 3072, 1024, 0, 1, 0, 0, 0, 0, 0, 0);
    // gated fuse (6-term: gate feeds routing via out)
    split_k<<<1024, 256, 0, stream>>>(fuse_w, wfuse, 10, 10, 6, PAT_B6, 262144);
    mgemm<2><<<dim3(8, 16, 1), 256, 0, stream>>>(hA6, wfuse, fuseb, 6144, 6144, 6144, 1024, 0, 1, 0, 0, 0, 0, 0, 0);
    fuse_k<<<(kBT * kD / 4) / 256, 256, 0, stream>>>(x, fuseb, ssmo, attno, out);
    // rmsnorm2 -> f32 (router) + bf16 (MoE A)
    rmsnorm_k<<<kBT, 256, 0, stream>>>(out, n2w, h2f, h2b, kD);
    // ternary quantization -> bf16 {-1,0,1}
    const float* wsrc[3] = {eg_w, eu_w, ed_w};
    u16* qdst[3] = {qg, qu, qd};
    for (int i = 0; i < 3; i++) {
        absmean_partial<<<1024, 256, 0, stream>>>(wsrc[i], part + i * 1024);
        thresh_k<<<1, 256, 0, stream>>>(part + i * 1024, thr + i);
        quantb_k<<<16384, 256, 0, stream>>>(wsrc[i], thr + i, qdst[i]);
    }
    // routing
    router_k<<<kBT / 4, 256, 0, stream>>>(h2f, rtr_w, topi, topw, counts, probs);
    route_offsets_k<<<1, 64, 0, stream>>>(counts, offs, cursor, pairT, pairW, tileE, tileB, nTiles);
    scatter_k<<<kBT / 256, 256, 0, stream>>>(topi, topw, cursor, pairT, pairW);
    // expert GEMMs (top-2 only, 128-padded tiles)
    moe_gu_m<<<dim3(kF / 64, 48, 1), 256, 0, stream>>>(h2b, qg, qu, eg_g, eu_g, tileE, tileB, nTiles, pairT, hh);
    moe_down_m<<<dim3(kD / 128, 48, 1), 256, 0, stream>>>(hh, qd, ed_g, tileE, tileB, nTiles, pairT, pairW, out);
    aux_k<<<1, 64, 0, stream>>>(probs, out + (size_t)kBT * kD);
}